// Round 1
// baseline (1618.901 us; speedup 1.0000x reference)
//
#include <hip/hip_runtime.h>
#include <hip/hip_bf16.h>

constexpr int FDIM = 128;

// ---------------- degree histogram (weighted + count) ----------------
__global__ __launch_bounds__(256) void k_hist(const int* __restrict__ col,
                                              const float* __restrict__ ew,
                                              float* __restrict__ deg,
                                              int* __restrict__ cnt, int E)
{
    int e = blockIdx.x * 256 + threadIdx.x;
    if (e >= E) return;
    int c = col[e];
    atomicAdd(&deg[c], ew[e]);
    atomicAdd(&cnt[c], 1);
}

// dis[i] = deg>0 ? rsqrt(max(deg,1e-20)) : 0   (deg includes self-loop +1)
__global__ __launch_bounds__(256) void k_dis(const float* __restrict__ deg,
                                             float* __restrict__ dis, int N)
{
    int i = blockIdx.x * 256 + threadIdx.x;
    if (i >= N) return;
    float d = deg[i] + 1.0f;
    float m = fmaxf(d, 1e-20f);
    dis[i] = (d > 0.0f) ? (1.0f / sqrtf(m)) : 0.0f;
}

// ---------------- 2-level exclusive scan for CSR offsets ----------------
__global__ __launch_bounds__(256) void k_blocksum(const int* __restrict__ cnt,
                                                  int* __restrict__ bsum, int n)
{
    __shared__ int s[256];
    int t = threadIdx.x;
    int i = blockIdx.x * 256 + t;
    s[t] = (i < n) ? cnt[i] : 0;
    __syncthreads();
    for (int o = 128; o > 0; o >>= 1) {
        if (t < o) s[t] += s[t + o];
        __syncthreads();
    }
    if (t == 0) bsum[blockIdx.x] = s[0];
}

__global__ __launch_bounds__(512) void k_scan_bsum(const int* __restrict__ bsum,
                                                   int* __restrict__ boff, int nb,
                                                   int* __restrict__ off, int N, int E)
{
    __shared__ int s[512];
    int t = threadIdx.x;
    int v = (t < nb) ? bsum[t] : 0;
    s[t] = v;
    __syncthreads();
    for (int o = 1; o < 512; o <<= 1) {
        int u = (t >= o) ? s[t - o] : 0;
        __syncthreads();
        s[t] += u;
        __syncthreads();
    }
    if (t < nb) boff[t] = s[t] - v;   // exclusive
    if (t == 0) off[N] = E;
}

__global__ __launch_bounds__(256) void k_offsets(const int* __restrict__ cnt,
                                                 const int* __restrict__ boff,
                                                 int* __restrict__ off, int n)
{
    __shared__ int s[256];
    int t = threadIdx.x;
    int i = blockIdx.x * 256 + t;
    int v = (i < n) ? cnt[i] : 0;
    s[t] = v;
    __syncthreads();
    for (int o = 1; o < 256; o <<= 1) {
        int u = (t >= o) ? s[t - o] : 0;
        __syncthreads();
        s[t] += u;
        __syncthreads();
    }
    if (i < n) off[i] = boff[blockIdx.x] + s[t] - v;
}

// ---------------- scatter edges into CSR (packed row + norm) ----------------
__global__ __launch_bounds__(256) void k_scatter(const int* __restrict__ row,
                                                 const int* __restrict__ col,
                                                 const float* __restrict__ ew,
                                                 const float* __restrict__ dis,
                                                 const int* __restrict__ off,
                                                 int* __restrict__ cnt,
                                                 int2* __restrict__ ep, int E)
{
    int e = blockIdx.x * 256 + threadIdx.x;
    if (e >= E) return;
    int r = row[e], c = col[e];
    float nrm = dis[r] * ew[e] * dis[c];
    int pos = off[c] + atomicAdd(&cnt[c], 1);
    ep[pos] = make_int2(r, __float_as_int(nrm));
}

// ---------------- SpMM: Y = A_hat @ X, one wave per destination node ----------------
__global__ __launch_bounds__(256) void k_spmm(const float2* __restrict__ X2,
                                              const int2* __restrict__ ep,
                                              const int* __restrict__ off,
                                              const float* __restrict__ dis,
                                              float2* __restrict__ Y2, int n)
{
    int gt = blockIdx.x * 256 + threadIdx.x;
    int node = gt >> 6;
    int lane = threadIdx.x & 63;
    if (node >= n) return;

    float s = dis[node];
    float sn = s * s;                       // self-loop norm = dis*1*dis
    float2 x0 = X2[(size_t)node * 64 + lane];
    float2 acc;
    acc.x = sn * x0.x;
    acc.y = sn * x0.y;

    int e = off[node];
    int end = off[node + 1];
    for (; e + 4 <= end; e += 4) {
        int2 p0 = ep[e + 0];
        int2 p1 = ep[e + 1];
        int2 p2 = ep[e + 2];
        int2 p3 = ep[e + 3];
        float2 a = X2[(size_t)p0.x * 64 + lane];
        float2 b = X2[(size_t)p1.x * 64 + lane];
        float2 c = X2[(size_t)p2.x * 64 + lane];
        float2 d = X2[(size_t)p3.x * 64 + lane];
        float w0 = __int_as_float(p0.y);
        float w1 = __int_as_float(p1.y);
        float w2 = __int_as_float(p2.y);
        float w3 = __int_as_float(p3.y);
        acc.x += w0 * a.x; acc.y += w0 * a.y;
        acc.x += w1 * b.x; acc.y += w1 * b.y;
        acc.x += w2 * c.x; acc.y += w2 * c.y;
        acc.x += w3 * d.x; acc.y += w3 * d.y;
    }
    for (; e < end; ++e) {
        int2 p = ep[e];
        float2 a = X2[(size_t)p.x * 64 + lane];
        float w = __int_as_float(p.y);
        acc.x += w * a.x; acc.y += w * a.y;
    }
    Y2[(size_t)node * 64 + lane] = acc;
}

// ---------------- fused GEMM: prod_{w<NW} tanh(Y @ W_w + b_w) ----------------
// Tile: 64 nodes x FOUT cols, 256 threads, micro-tile NPT x 8.
template <int FOUT, int NW>
__global__ __launch_bounds__(256, 1) void k_gemm(const float* __restrict__ Yg,
                                                 const float* __restrict__ W0p, const float* __restrict__ B0p,
                                                 const float* __restrict__ W1p, const float* __restrict__ B1p,
                                                 const float* __restrict__ W2p, const float* __restrict__ B2p,
                                                 float* __restrict__ Out, int nRows)
{
    constexpr int K = 128;
    constexpr int TX = FOUT / 8;    // 16 (FOUT=128) or 8 (FOUT=64)
    constexpr int TY = 256 / TX;    // 16 or 32
    constexpr int NPT = 64 / TY;    // 4 or 2
    constexpr int YS = K + 4;       // padded stride: kills stride-128 bank conflicts

    __shared__ float Ylds[64 * YS];
    __shared__ float Wlds[K * FOUT];

    int tid = threadIdx.x;
    int row0 = blockIdx.x * 64;

    // stage Y tile (64 x 128) as float4
    {
        const float4* Y4 = (const float4*)Yg;
        #pragma unroll
        for (int idx = tid; idx < 64 * 32; idx += 256) {
            int r = idx >> 5, c = idx & 31;
            float4 v = (row0 + r < nRows) ? Y4[(size_t)(row0 + r) * 32 + c]
                                          : make_float4(0.f, 0.f, 0.f, 0.f);
            *(float4*)&Ylds[r * YS + c * 4] = v;
        }
    }

    int tx = tid % TX, ty = tid / TX;
    int c0 = tx * 8;

    const float* Ws[3] = {W0p, W1p, W2p};
    const float* Bs[3] = {B0p, B1p, B2p};
    float prod[NPT][8];

    #pragma unroll
    for (int w = 0; w < NW; ++w) {
        __syncthreads();   // previous pass done reading Wlds (and Y staged, pass 0)
        {
            const float4* Wg4 = (const float4*)Ws[w];
            #pragma unroll
            for (int idx = tid; idx < K * FOUT / 4; idx += 256)
                *(float4*)&Wlds[idx * 4] = Wg4[idx];
        }
        __syncthreads();

        float acc[NPT][8];
        #pragma unroll
        for (int i = 0; i < NPT; ++i)
            #pragma unroll
            for (int j = 0; j < 8; ++j) acc[i][j] = 0.f;

        #pragma unroll 8
        for (int k = 0; k < K; ++k) {
            float yv[NPT];
            #pragma unroll
            for (int i = 0; i < NPT; ++i)
                yv[i] = Ylds[(ty * NPT + i) * YS + k];
            float wv[8];
            *(float4*)&wv[0] = *(const float4*)&Wlds[k * FOUT + c0];
            *(float4*)&wv[4] = *(const float4*)&Wlds[k * FOUT + c0 + 4];
            #pragma unroll
            for (int i = 0; i < NPT; ++i)
                #pragma unroll
                for (int j = 0; j < 8; ++j)
                    acc[i][j] += yv[i] * wv[j];
        }

        float bj[8];
        *(float4*)&bj[0] = *(const float4*)&Bs[w][c0];
        *(float4*)&bj[4] = *(const float4*)&Bs[w][c0 + 4];
        #pragma unroll
        for (int i = 0; i < NPT; ++i)
            #pragma unroll
            for (int j = 0; j < 8; ++j) {
                float t = tanhf(acc[i][j] + bj[j]);
                prod[i][j] = (w == 0) ? t : prod[i][j] * t;
            }
    }

    #pragma unroll
    for (int i = 0; i < NPT; ++i) {
        int r = row0 + ty * NPT + i;
        if (r < nRows) {
            *(float4*)&Out[(size_t)r * FOUT + c0] =
                make_float4(prod[i][0], prod[i][1], prod[i][2], prod[i][3]);
            *(float4*)&Out[(size_t)r * FOUT + c0 + 4] =
                make_float4(prod[i][4], prod[i][5], prod[i][6], prod[i][7]);
        }
    }
}

extern "C" void kernel_launch(void* const* d_in, const int* in_sizes, int n_in,
                              void* d_out, int out_size, void* d_ws, size_t ws_size,
                              hipStream_t stream)
{
    const float* h0 = (const float*)d_in[0];
    const int*   ei = (const int*)d_in[1];
    const float* ew = (const float*)d_in[2];
    const float* W1 = (const float*)d_in[3];  const float* b1 = (const float*)d_in[4];
    const float* W2 = (const float*)d_in[5];  const float* b2 = (const float*)d_in[6];
    const float* W3 = (const float*)d_in[7];  const float* b3 = (const float*)d_in[8];
    const float* W4 = (const float*)d_in[9];  const float* b4 = (const float*)d_in[10];
    const float* W5 = (const float*)d_in[11]; const float* b5 = (const float*)d_in[12];
    const float* W6 = (const float*)d_in[13]; const float* b6 = (const float*)d_in[14];

    const int N = in_sizes[0] / FDIM;
    const int E = in_sizes[2];
    const int* rowp = ei;
    const int* colp = ei + E;

    char* p = (char*)d_ws;
    auto alloc = [&](size_t bytes) -> void* {
        void* r = (void*)p;
        p += (bytes + 255) & ~(size_t)255;
        return r;
    };
    float* deg  = (float*)alloc((size_t)N * 4);
    float* dis  = (float*)alloc((size_t)N * 4);
    int*   cnt  = (int*)  alloc((size_t)N * 4);
    int*   off  = (int*)  alloc((size_t)(N + 1) * 4);
    const int NB = (N + 255) / 256;
    int*   bsum = (int*)  alloc((size_t)NB * 4);
    int*   boff = (int*)  alloc((size_t)NB * 4);
    int2*  ep   = (int2*) alloc((size_t)E * 8);
    float* Y    = (float*)alloc((size_t)N * FDIM * 4);
    float* H    = (float*)alloc((size_t)N * FDIM * 4);

    hipMemsetAsync(deg, 0, (size_t)N * 4, stream);
    hipMemsetAsync(cnt, 0, (size_t)N * 4, stream);

    const int eb = (E + 255) / 256;
    k_hist<<<eb, 256, 0, stream>>>(colp, ew, deg, cnt, E);
    k_dis<<<NB, 256, 0, stream>>>(deg, dis, N);
    k_blocksum<<<NB, 256, 0, stream>>>(cnt, bsum, N);
    k_scan_bsum<<<1, 512, 0, stream>>>(bsum, boff, NB, off, N, E);
    k_offsets<<<NB, 256, 0, stream>>>(cnt, boff, off, N);
    hipMemsetAsync(cnt, 0, (size_t)N * 4, stream);
    k_scatter<<<eb, 256, 0, stream>>>(rowp, colp, ew, dis, off, cnt, ep, E);

    const int sb = (N + 3) / 4;     // 4 waves (nodes) per 256-thread block
    const int gb = (N + 63) / 64;   // 64-node tiles

    // Stage A: Y0 = A_hat @ h0 ; h123 = tanh(Y0 W1+b1)*tanh(Y0 W2+b2)*tanh(Y0 W3+b3)
    k_spmm<<<sb, 256, 0, stream>>>((const float2*)h0, ep, off, dis, (float2*)Y, N);
    k_gemm<128, 3><<<gb, 256, 0, stream>>>(Y, W1, b1, W2, b2, W3, b3, H, N);
    // Stage B: Z = A_hat @ h123 ; h45 = tanh(Z W4+b4)*tanh(Z W5+b5)
    k_spmm<<<sb, 256, 0, stream>>>((const float2*)H, ep, off, dis, (float2*)Y, N);
    k_gemm<128, 2><<<gb, 256, 0, stream>>>(Y, W4, b4, W5, b5, nullptr, nullptr, H, N);
    // Stage C: U = A_hat @ h45 ; out = tanh(U W6 + b6)
    k_spmm<<<sb, 256, 0, stream>>>((const float2*)H, ep, off, dis, (float2*)Y, N);
    k_gemm<64, 1><<<gb, 256, 0, stream>>>(Y, W6, b6, nullptr, nullptr, nullptr, nullptr,
                                          (float*)d_out, N);
}

// Round 2
// 1543.943 us; speedup vs baseline: 1.0485x; 1.0485x over previous
//
#include <hip/hip_runtime.h>
#include <hip/hip_bf16.h>

constexpr int FDIM = 128;

// ---------------- degree histogram (weighted + count) ----------------
__global__ __launch_bounds__(256) void k_hist(const int* __restrict__ col,
                                              const float* __restrict__ ew,
                                              float* __restrict__ deg,
                                              int* __restrict__ cnt, int E)
{
    int e = blockIdx.x * 256 + threadIdx.x;
    if (e >= E) return;
    int c = col[e];
    atomicAdd(&deg[c], ew[e]);
    atomicAdd(&cnt[c], 1);
}

__global__ __launch_bounds__(256) void k_dis(const float* __restrict__ deg,
                                             float* __restrict__ dis, int N)
{
    int i = blockIdx.x * 256 + threadIdx.x;
    if (i >= N) return;
    float d = deg[i] + 1.0f;
    float m = fmaxf(d, 1e-20f);
    dis[i] = (d > 0.0f) ? (1.0f / sqrtf(m)) : 0.0f;
}

// ---------------- 2-level exclusive scan for CSR offsets ----------------
__global__ __launch_bounds__(256) void k_blocksum(const int* __restrict__ cnt,
                                                  int* __restrict__ bsum, int n)
{
    __shared__ int s[256];
    int t = threadIdx.x;
    int i = blockIdx.x * 256 + t;
    s[t] = (i < n) ? cnt[i] : 0;
    __syncthreads();
    for (int o = 128; o > 0; o >>= 1) {
        if (t < o) s[t] += s[t + o];
        __syncthreads();
    }
    if (t == 0) bsum[blockIdx.x] = s[0];
}

__global__ __launch_bounds__(512) void k_scan_bsum(const int* __restrict__ bsum,
                                                   int* __restrict__ boff, int nb,
                                                   int* __restrict__ off, int N, int E)
{
    __shared__ int s[512];
    int t = threadIdx.x;
    int v = (t < nb) ? bsum[t] : 0;
    s[t] = v;
    __syncthreads();
    for (int o = 1; o < 512; o <<= 1) {
        int u = (t >= o) ? s[t - o] : 0;
        __syncthreads();
        s[t] += u;
        __syncthreads();
    }
    if (t < nb) boff[t] = s[t] - v;   // exclusive
    if (t == 0) off[N] = E;
}

__global__ __launch_bounds__(256) void k_offsets(const int* __restrict__ cnt,
                                                 const int* __restrict__ boff,
                                                 int* __restrict__ off, int n)
{
    __shared__ int s[256];
    int t = threadIdx.x;
    int i = blockIdx.x * 256 + t;
    int v = (i < n) ? cnt[i] : 0;
    s[t] = v;
    __syncthreads();
    for (int o = 1; o < 256; o <<= 1) {
        int u = (t >= o) ? s[t - o] : 0;
        __syncthreads();
        s[t] += u;
        __syncthreads();
    }
    if (i < n) off[i] = boff[blockIdx.x] + s[t] - v;
}

// ---------------- scatter edges into CSR (packed row + norm) ----------------
__global__ __launch_bounds__(256) void k_scatter(const int* __restrict__ row,
                                                 const int* __restrict__ col,
                                                 const float* __restrict__ ew,
                                                 const float* __restrict__ dis,
                                                 const int* __restrict__ off,
                                                 int* __restrict__ cnt,
                                                 int2* __restrict__ ep, int E)
{
    int e = blockIdx.x * 256 + threadIdx.x;
    if (e >= E) return;
    int r = row[e], c = col[e];
    float nrm = dis[r] * ew[e] * dis[c];
    int pos = off[c] + atomicAdd(&cnt[c], 1);
    ep[pos] = make_int2(r, __float_as_int(nrm));
}

// ---------------- SpMM: Y = A_hat @ X, one wave per destination node ----------------
// 2-deep software pipeline: ep(b+2) + gathers(b+1) in flight while computing batch b.
__global__ __launch_bounds__(256) void k_spmm(const float2* __restrict__ X2,
                                              const int2* __restrict__ ep,
                                              const int* __restrict__ off,
                                              const float* __restrict__ dis,
                                              float2* __restrict__ Y2, int n)
{
    int gt = blockIdx.x * 256 + threadIdx.x;
    int node = gt >> 6;
    int lane = threadIdx.x & 63;
    if (node >= n) return;

    float s = dis[node];
    float sn = s * s;                       // self-loop norm
    float2 x0 = X2[(size_t)node * 64 + lane];
    float a0x = sn * x0.x, a0y = sn * x0.y;
    float a1x = 0.f, a1y = 0.f;
    float a2x = 0.f, a2y = 0.f;
    float a3x = 0.f, a3y = 0.f;

    const int e0 = off[node];
    const int cnt = off[node + 1] - e0;
    const int2* el = ep + e0;
    const int nb = cnt >> 2;
    int done = 0;

    if (nb >= 2) {
        int2 q0, q1, q2, q3;
        // batch 0 ep + gather
        int2 p0 = el[0], p1 = el[1], p2 = el[2], p3 = el[3];
        q0 = el[4]; q1 = el[5]; q2 = el[6]; q3 = el[7];
        float2 xc0 = X2[(size_t)p0.x * 64 + lane];
        float2 xc1 = X2[(size_t)p1.x * 64 + lane];
        float2 xc2 = X2[(size_t)p2.x * 64 + lane];
        float2 xc3 = X2[(size_t)p3.x * 64 + lane];
        float wc0 = __int_as_float(p0.y), wc1 = __int_as_float(p1.y);
        float wc2 = __int_as_float(p2.y), wc3 = __int_as_float(p3.y);

        int b;
        #pragma unroll 2
        for (b = 0; b + 2 < nb; ++b) {
            // gather batch b+1
            float2 xn0 = X2[(size_t)q0.x * 64 + lane];
            float2 xn1 = X2[(size_t)q1.x * 64 + lane];
            float2 xn2 = X2[(size_t)q2.x * 64 + lane];
            float2 xn3 = X2[(size_t)q3.x * 64 + lane];
            float wn0 = __int_as_float(q0.y), wn1 = __int_as_float(q1.y);
            float wn2 = __int_as_float(q2.y), wn3 = __int_as_float(q3.y);
            // ep batch b+2
            const int2* eb = el + (size_t)(b + 2) * 4;
            q0 = eb[0]; q1 = eb[1]; q2 = eb[2]; q3 = eb[3];
            // compute batch b
            a0x += wc0 * xc0.x; a0y += wc0 * xc0.y;
            a1x += wc1 * xc1.x; a1y += wc1 * xc1.y;
            a2x += wc2 * xc2.x; a2y += wc2 * xc2.y;
            a3x += wc3 * xc3.x; a3y += wc3 * xc3.y;
            xc0 = xn0; xc1 = xn1; xc2 = xn2; xc3 = xn3;
            wc0 = wn0; wc1 = wn1; wc2 = wn2; wc3 = wn3;
        }
        // epilogue: batches nb-2 (xc ready) and nb-1 (gather from q)
        float2 xn0 = X2[(size_t)q0.x * 64 + lane];
        float2 xn1 = X2[(size_t)q1.x * 64 + lane];
        float2 xn2 = X2[(size_t)q2.x * 64 + lane];
        float2 xn3 = X2[(size_t)q3.x * 64 + lane];
        float wn0 = __int_as_float(q0.y), wn1 = __int_as_float(q1.y);
        float wn2 = __int_as_float(q2.y), wn3 = __int_as_float(q3.y);
        a0x += wc0 * xc0.x; a0y += wc0 * xc0.y;
        a1x += wc1 * xc1.x; a1y += wc1 * xc1.y;
        a2x += wc2 * xc2.x; a2y += wc2 * xc2.y;
        a3x += wc3 * xc3.x; a3y += wc3 * xc3.y;
        a0x += wn0 * xn0.x; a0y += wn0 * xn0.y;
        a1x += wn1 * xn1.x; a1y += wn1 * xn1.y;
        a2x += wn2 * xn2.x; a2y += wn2 * xn2.y;
        a3x += wn3 * xn3.x; a3y += wn3 * xn3.y;
        done = nb * 4;
    }
    for (int e = done; e < cnt; ++e) {
        int2 p = el[e];
        float2 xv = X2[(size_t)p.x * 64 + lane];
        float w = __int_as_float(p.y);
        a0x += w * xv.x; a0y += w * xv.y;
    }
    float2 r;
    r.x = (a0x + a1x) + (a2x + a3x);
    r.y = (a0y + a1y) + (a2y + a3y);
    Y2[(size_t)node * 64 + lane] = r;
}

// fast tanh: 1 - 2/(e^{2x}+1) via v_exp + v_rcp (branch-free, correct at +-inf)
__device__ __forceinline__ float fast_tanh(float x) {
    float e = __expf(2.0f * x);
    return 1.0f - 2.0f * __builtin_amdgcn_rcpf(e + 1.0f);
}

// ---------------- fused GEMM: prod_{w<NW} tanh(Y @ W_w + b_w) ----------------
// 64 rows x FOUT cols per block; Y in LDS (YS=129, conflict-free), W streamed
// from global (L1/L2-served, block-uniform). No per-pass syncs.
template <int FOUT, int NW, bool PRECISE>
__global__ __launch_bounds__(256, 4) void k_gemm(const float* __restrict__ Yg,
                                                 const float* __restrict__ W0p, const float* __restrict__ B0p,
                                                 const float* __restrict__ W1p, const float* __restrict__ B1p,
                                                 const float* __restrict__ W2p, const float* __restrict__ B2p,
                                                 float* __restrict__ Out, int nRows)
{
    constexpr int K = 128;
    constexpr int TX = FOUT / 8;    // 16 (FOUT=128) or 8 (FOUT=64)
    constexpr int TY = 256 / TX;    // 16 or 32
    constexpr int NPT = 64 / TY;    // 4 or 2
    constexpr int YS = K + 1;       // 129: per-wave row-group stride hits distinct banks

    __shared__ float Ylds[64 * YS];

    int tid = threadIdx.x;
    int row0 = blockIdx.x * 64;

    // stage Y tile (64 x 128): float4 global reads, scalar LDS writes
    {
        const float4* Y4 = (const float4*)Yg;
        #pragma unroll
        for (int it = 0; it < 8; ++it) {
            int idx = it * 256 + tid;
            int r = idx >> 5, c = (idx & 31) << 2;
            float4 v = (row0 + r < nRows) ? Y4[(size_t)(row0 + r) * 32 + (c >> 2)]
                                          : make_float4(0.f, 0.f, 0.f, 0.f);
            Ylds[r * YS + c + 0] = v.x;
            Ylds[r * YS + c + 1] = v.y;
            Ylds[r * YS + c + 2] = v.z;
            Ylds[r * YS + c + 3] = v.w;
        }
    }
    __syncthreads();

    int tx = tid % TX, ty = tid / TX;
    int c0 = tx * 8;
    int ry = ty * NPT;

    const float* Ws[3] = {W0p, W1p, W2p};
    const float* Bs[3] = {B0p, B1p, B2p};
    float prod[NPT][8];

    #pragma unroll
    for (int w = 0; w < NW; ++w) {
        const float* Wp = Ws[w] + c0;
        float acc[NPT][8];
        #pragma unroll
        for (int i = 0; i < NPT; ++i)
            #pragma unroll
            for (int j = 0; j < 8; ++j) acc[i][j] = 0.f;

        #pragma unroll 4
        for (int k = 0; k < K; ++k) {
            float wv[8];
            *(float4*)&wv[0] = *(const float4*)(Wp + (size_t)k * FOUT);
            *(float4*)&wv[4] = *(const float4*)(Wp + (size_t)k * FOUT + 4);
            float yv[NPT];
            #pragma unroll
            for (int i = 0; i < NPT; ++i)
                yv[i] = Ylds[(ry + i) * YS + k];
            #pragma unroll
            for (int i = 0; i < NPT; ++i)
                #pragma unroll
                for (int j = 0; j < 8; ++j)
                    acc[i][j] += yv[i] * wv[j];
        }

        float bj[8];
        #pragma unroll
        for (int j = 0; j < 8; ++j) bj[j] = Bs[w][c0 + j];
        #pragma unroll
        for (int i = 0; i < NPT; ++i)
            #pragma unroll
            for (int j = 0; j < 8; ++j) {
                float pre = acc[i][j] + bj[j];
                float t = PRECISE ? tanhf(pre) : fast_tanh(pre);
                prod[i][j] = (w == 0) ? t : prod[i][j] * t;
            }
    }

    #pragma unroll
    for (int i = 0; i < NPT; ++i) {
        int r = row0 + ry + i;
        if (r < nRows) {
            *(float4*)&Out[(size_t)r * FOUT + c0] =
                make_float4(prod[i][0], prod[i][1], prod[i][2], prod[i][3]);
            *(float4*)&Out[(size_t)r * FOUT + c0 + 4] =
                make_float4(prod[i][4], prod[i][5], prod[i][6], prod[i][7]);
        }
    }
}

extern "C" void kernel_launch(void* const* d_in, const int* in_sizes, int n_in,
                              void* d_out, int out_size, void* d_ws, size_t ws_size,
                              hipStream_t stream)
{
    const float* h0 = (const float*)d_in[0];
    const int*   ei = (const int*)d_in[1];
    const float* ew = (const float*)d_in[2];
    const float* W1 = (const float*)d_in[3];  const float* b1 = (const float*)d_in[4];
    const float* W2 = (const float*)d_in[5];  const float* b2 = (const float*)d_in[6];
    const float* W3 = (const float*)d_in[7];  const float* b3 = (const float*)d_in[8];
    const float* W4 = (const float*)d_in[9];  const float* b4 = (const float*)d_in[10];
    const float* W5 = (const float*)d_in[11]; const float* b5 = (const float*)d_in[12];
    const float* W6 = (const float*)d_in[13]; const float* b6 = (const float*)d_in[14];

    const int N = in_sizes[0] / FDIM;
    const int E = in_sizes[2];
    const int* rowp = ei;
    const int* colp = ei + E;

    char* p = (char*)d_ws;
    auto alloc = [&](size_t bytes) -> void* {
        void* r = (void*)p;
        p += (bytes + 255) & ~(size_t)255;
        return r;
    };
    float* deg  = (float*)alloc((size_t)N * 4);
    float* dis  = (float*)alloc((size_t)N * 4);
    int*   cnt  = (int*)  alloc((size_t)N * 4);
    int*   off  = (int*)  alloc((size_t)(N + 1) * 4);
    const int NB = (N + 255) / 256;
    int*   bsum = (int*)  alloc((size_t)NB * 4);
    int*   boff = (int*)  alloc((size_t)NB * 4);
    int2*  ep   = (int2*) alloc((size_t)E * 8);
    float* Y    = (float*)alloc((size_t)N * FDIM * 4);
    float* H    = (float*)alloc((size_t)N * FDIM * 4);

    hipMemsetAsync(deg, 0, (size_t)N * 4, stream);
    hipMemsetAsync(cnt, 0, (size_t)N * 4, stream);

    const int eb = (E + 255) / 256;
    k_hist<<<eb, 256, 0, stream>>>(colp, ew, deg, cnt, E);
    k_dis<<<NB, 256, 0, stream>>>(deg, dis, N);
    k_blocksum<<<NB, 256, 0, stream>>>(cnt, bsum, N);
    k_scan_bsum<<<1, 512, 0, stream>>>(bsum, boff, NB, off, N, E);
    k_offsets<<<NB, 256, 0, stream>>>(cnt, boff, off, N);
    hipMemsetAsync(cnt, 0, (size_t)N * 4, stream);
    k_scatter<<<eb, 256, 0, stream>>>(rowp, colp, ew, dis, off, cnt, ep, E);

    const int sb = (N + 3) / 4;     // 4 waves (nodes) per 256-thread block
    const int gb = (N + 63) / 64;   // 64-node tiles

    // Stage A
    k_spmm<<<sb, 256, 0, stream>>>((const float2*)h0, ep, off, dis, (float2*)Y, N);
    k_gemm<128, 3, false><<<gb, 256, 0, stream>>>(Y, W1, b1, W2, b2, W3, b3, H, N);
    // Stage B
    k_spmm<<<sb, 256, 0, stream>>>((const float2*)H, ep, off, dis, (float2*)Y, N);
    k_gemm<128, 2, false><<<gb, 256, 0, stream>>>(Y, W4, b4, W5, b5, nullptr, nullptr, H, N);
    // Stage C
    k_spmm<<<sb, 256, 0, stream>>>((const float2*)H, ep, off, dis, (float2*)Y, N);
    k_gemm<64, 1, true><<<gb, 256, 0, stream>>>(Y, W6, b6, nullptr, nullptr, nullptr, nullptr,
                                                (float*)d_out, N);
}

// Round 3
// 1057.040 us; speedup vs baseline: 1.5315x; 1.4606x over previous
//
#include <hip/hip_runtime.h>
#include <hip/hip_bf16.h>
#include <hip/hip_fp16.h>

constexpr int FDIM = 128;
#define HSCALE 16384.0f         // 2^14: |h|<1 -> scaled <16384 <= 65504, always safe
#define HSCALE_INV (1.0f/16384.0f)

// ---------------- packed histogram: one 64-bit atomic per edge ----------------
// bits [0,44): sum(w) in 2^-32 fixed point (max ~70*2^32 = 2^38.2, no overflow)
// bits [44,64): count
__global__ __launch_bounds__(256) void k_hist(const int* __restrict__ col,
                                              const float* __restrict__ ew,
                                              unsigned long long* __restrict__ packed, int E)
{
    int e = blockIdx.x * 256 + threadIdx.x;
    if (e >= E) return;
    int c = col[e];
    unsigned long long v = (1ull << 44) |
        (unsigned long long)((double)ew[e] * 4294967296.0);
    atomicAdd(&packed[c], v);
}

// unpack: cnt for scan, dis = rsqrt(deg+1)
__global__ __launch_bounds__(256) void k_dis(const unsigned long long* __restrict__ packed,
                                             int* __restrict__ cnt,
                                             float* __restrict__ dis, int N)
{
    int i = blockIdx.x * 256 + threadIdx.x;
    if (i >= N) return;
    unsigned long long p = packed[i];
    cnt[i] = (int)(p >> 44);
    float d = (float)((double)(p & 0xFFFFFFFFFFFull) * (1.0 / 4294967296.0)) + 1.0f;
    float m = fmaxf(d, 1e-20f);
    dis[i] = (d > 0.0f) ? (1.0f / sqrtf(m)) : 0.0f;
}

// ---------------- 2-level exclusive scan for CSR offsets ----------------
__global__ __launch_bounds__(256) void k_blocksum(const int* __restrict__ cnt,
                                                  int* __restrict__ bsum, int n)
{
    __shared__ int s[256];
    int t = threadIdx.x;
    int i = blockIdx.x * 256 + t;
    s[t] = (i < n) ? cnt[i] : 0;
    __syncthreads();
    for (int o = 128; o > 0; o >>= 1) {
        if (t < o) s[t] += s[t + o];
        __syncthreads();
    }
    if (t == 0) bsum[blockIdx.x] = s[0];
}

__global__ __launch_bounds__(512) void k_scan_bsum(const int* __restrict__ bsum,
                                                   int* __restrict__ boff, int nb,
                                                   int* __restrict__ off, int N, int E)
{
    __shared__ int s[512];
    int t = threadIdx.x;
    int v = (t < nb) ? bsum[t] : 0;
    s[t] = v;
    __syncthreads();
    for (int o = 1; o < 512; o <<= 1) {
        int u = (t >= o) ? s[t - o] : 0;
        __syncthreads();
        s[t] += u;
        __syncthreads();
    }
    if (t < nb) boff[t] = s[t] - v;   // exclusive
    if (t == 0) off[N] = E;
}

__global__ __launch_bounds__(256) void k_offsets(const int* __restrict__ cnt,
                                                 const int* __restrict__ boff,
                                                 int* __restrict__ off, int n)
{
    __shared__ int s[256];
    int t = threadIdx.x;
    int i = blockIdx.x * 256 + t;
    int v = (i < n) ? cnt[i] : 0;
    s[t] = v;
    __syncthreads();
    for (int o = 1; o < 256; o <<= 1) {
        int u = (t >= o) ? s[t - o] : 0;
        __syncthreads();
        s[t] += u;
        __syncthreads();
    }
    if (i < n) off[i] = boff[blockIdx.x] + s[t] - v;
}

// ---------------- scatter edges into CSR (atomicSub reuses cnt, no re-zero) ----------------
__global__ __launch_bounds__(256) void k_scatter(const int* __restrict__ row,
                                                 const int* __restrict__ col,
                                                 const float* __restrict__ ew,
                                                 const float* __restrict__ dis,
                                                 const int* __restrict__ off,
                                                 int* __restrict__ cnt,
                                                 int2* __restrict__ ep, int E)
{
    int e = blockIdx.x * 256 + threadIdx.x;
    if (e >= E) return;
    int r = row[e], c = col[e];
    float nrm = dis[r] * ew[e] * dis[c];
    int old = atomicSub(&cnt[c], 1);        // old in [1..cnt]
    int pos = off[c + 1] - old;             // in [off[c], off[c+1])
    ep[pos] = make_int2(r, __float_as_int(nrm));
}

// ---------------- f32 -> f16 convert (stage A input) ----------------
__global__ __launch_bounds__(256) void k_cvt(const float4* __restrict__ in,
                                             __half2* __restrict__ out, int n4)
{
    int i = blockIdx.x * 256 + threadIdx.x;
    if (i >= n4) return;
    float4 v = in[i];
    __half2 a = __floats2half2_rn(v.x, v.y);
    __half2 b = __floats2half2_rn(v.z, v.w);
    float2 pk;
    ((__half2*)&pk)[0] = a;
    ((__half2*)&pk)[1] = b;
    *(float2*)&out[(size_t)i * 2] = pk;
}

// ---------------- SpMM: Y = A_hat @ X (fp16 rows, fp32 accum) ----------------
// one wave per node; 2-deep pipeline: ep(b+2) + gathers(b+1) in flight over compute(b)
__global__ __launch_bounds__(256) void k_spmm(const __half2* __restrict__ Xh,
                                              const int2* __restrict__ ep,
                                              const int* __restrict__ off,
                                              const float* __restrict__ dis,
                                              float2* __restrict__ Y2, int n)
{
    int gt = blockIdx.x * 256 + threadIdx.x;
    int node = gt >> 6;
    int lane = threadIdx.x & 63;
    if (node >= n) return;

    float s = dis[node];
    float sn = s * s;                       // self-loop norm
    float2 x0 = __half22float2(Xh[(size_t)node * 64 + lane]);
    float a0x = sn * x0.x, a0y = sn * x0.y;
    float a1x = 0.f, a1y = 0.f;
    float a2x = 0.f, a2y = 0.f;
    float a3x = 0.f, a3y = 0.f;

    const int e0 = off[node];
    const int cnt = off[node + 1] - e0;
    const int2* el = ep + e0;
    const int nb = cnt >> 2;
    int done = 0;

    if (nb >= 2) {
        int2 q0, q1, q2, q3;
        int2 p0 = el[0], p1 = el[1], p2 = el[2], p3 = el[3];
        q0 = el[4]; q1 = el[5]; q2 = el[6]; q3 = el[7];
        __half2 xc0 = Xh[(size_t)p0.x * 64 + lane];
        __half2 xc1 = Xh[(size_t)p1.x * 64 + lane];
        __half2 xc2 = Xh[(size_t)p2.x * 64 + lane];
        __half2 xc3 = Xh[(size_t)p3.x * 64 + lane];
        float wc0 = __int_as_float(p0.y), wc1 = __int_as_float(p1.y);
        float wc2 = __int_as_float(p2.y), wc3 = __int_as_float(p3.y);

        int b;
        #pragma unroll 2
        for (b = 0; b + 2 < nb; ++b) {
            __half2 xn0 = Xh[(size_t)q0.x * 64 + lane];
            __half2 xn1 = Xh[(size_t)q1.x * 64 + lane];
            __half2 xn2 = Xh[(size_t)q2.x * 64 + lane];
            __half2 xn3 = Xh[(size_t)q3.x * 64 + lane];
            float wn0 = __int_as_float(q0.y), wn1 = __int_as_float(q1.y);
            float wn2 = __int_as_float(q2.y), wn3 = __int_as_float(q3.y);
            const int2* eb = el + (size_t)(b + 2) * 4;
            q0 = eb[0]; q1 = eb[1]; q2 = eb[2]; q3 = eb[3];
            float2 f0 = __half22float2(xc0), f1 = __half22float2(xc1);
            float2 f2 = __half22float2(xc2), f3 = __half22float2(xc3);
            a0x += wc0 * f0.x; a0y += wc0 * f0.y;
            a1x += wc1 * f1.x; a1y += wc1 * f1.y;
            a2x += wc2 * f2.x; a2y += wc2 * f2.y;
            a3x += wc3 * f3.x; a3y += wc3 * f3.y;
            xc0 = xn0; xc1 = xn1; xc2 = xn2; xc3 = xn3;
            wc0 = wn0; wc1 = wn1; wc2 = wn2; wc3 = wn3;
        }
        __half2 xn0 = Xh[(size_t)q0.x * 64 + lane];
        __half2 xn1 = Xh[(size_t)q1.x * 64 + lane];
        __half2 xn2 = Xh[(size_t)q2.x * 64 + lane];
        __half2 xn3 = Xh[(size_t)q3.x * 64 + lane];
        float wn0 = __int_as_float(q0.y), wn1 = __int_as_float(q1.y);
        float wn2 = __int_as_float(q2.y), wn3 = __int_as_float(q3.y);
        {
            float2 f0 = __half22float2(xc0), f1 = __half22float2(xc1);
            float2 f2 = __half22float2(xc2), f3 = __half22float2(xc3);
            a0x += wc0 * f0.x; a0y += wc0 * f0.y;
            a1x += wc1 * f1.x; a1y += wc1 * f1.y;
            a2x += wc2 * f2.x; a2y += wc2 * f2.y;
            a3x += wc3 * f3.x; a3y += wc3 * f3.y;
        }
        {
            float2 f0 = __half22float2(xn0), f1 = __half22float2(xn1);
            float2 f2 = __half22float2(xn2), f3 = __half22float2(xn3);
            a0x += wn0 * f0.x; a0y += wn0 * f0.y;
            a1x += wn1 * f1.x; a1y += wn1 * f1.y;
            a2x += wn2 * f2.x; a2y += wn2 * f2.y;
            a3x += wn3 * f3.x; a3y += wn3 * f3.y;
        }
        done = nb * 4;
    }
    for (int e = done; e < cnt; ++e) {
        int2 p = el[e];
        float2 xv = __half22float2(Xh[(size_t)p.x * 64 + lane]);
        float w = __int_as_float(p.y);
        a0x += w * xv.x; a0y += w * xv.y;
    }
    float2 r;
    r.x = (a0x + a1x) + (a2x + a3x);
    r.y = (a0y + a1y) + (a2y + a3y);
    Y2[(size_t)node * 64 + lane] = r;
}

// fast tanh: 1 - 2/(e^{2x}+1) via v_exp + v_rcp
__device__ __forceinline__ float fast_tanh(float x) {
    float e = __expf(2.0f * x);
    return 1.0f - 2.0f * __builtin_amdgcn_rcpf(e + 1.0f);
}

// ---------------- fused GEMM: prod_{w<NW} tanh(IS * (Y @ W_w) + b_w) ----------------
// Y tile in LDS (YS=129, conflict-free); W streamed from global (L1/L2 broadcast).
// HOUT: write fp16 scaled by OS; else fp32 (times OS).
template <int FOUT, int NW, bool PRECISE, bool HOUT>
__global__ __launch_bounds__(256, 4) void k_gemm(const float* __restrict__ Yg,
                                                 float IS, float OS,
                                                 const float* __restrict__ W0p, const float* __restrict__ B0p,
                                                 const float* __restrict__ W1p, const float* __restrict__ B1p,
                                                 const float* __restrict__ W2p, const float* __restrict__ B2p,
                                                 void* __restrict__ Outv, int nRows)
{
    constexpr int K = 128;
    constexpr int TX = FOUT / 8;    // 16 (FOUT=128) or 8 (FOUT=64)
    constexpr int TY = 256 / TX;    // 16 or 32
    constexpr int NPT = 64 / TY;    // 4 or 2
    constexpr int YS = K + 1;       // 129: conflict-free column reads

    __shared__ float Ylds[64 * YS];

    int tid = threadIdx.x;
    int row0 = blockIdx.x * 64;

    {
        const float4* Y4 = (const float4*)Yg;
        #pragma unroll
        for (int it = 0; it < 8; ++it) {
            int idx = it * 256 + tid;
            int r = idx >> 5, c = (idx & 31) << 2;
            float4 v = (row0 + r < nRows) ? Y4[(size_t)(row0 + r) * 32 + (c >> 2)]
                                          : make_float4(0.f, 0.f, 0.f, 0.f);
            Ylds[r * YS + c + 0] = v.x;
            Ylds[r * YS + c + 1] = v.y;
            Ylds[r * YS + c + 2] = v.z;
            Ylds[r * YS + c + 3] = v.w;
        }
    }
    __syncthreads();

    int tx = tid % TX, ty = tid / TX;
    int c0 = tx * 8;
    int ry = ty * NPT;

    const float* Ws[3] = {W0p, W1p, W2p};
    const float* Bs[3] = {B0p, B1p, B2p};
    float prod[NPT][8];

    #pragma unroll
    for (int w = 0; w < NW; ++w) {
        const float* Wp = Ws[w] + c0;
        float acc[NPT][8];
        #pragma unroll
        for (int i = 0; i < NPT; ++i)
            #pragma unroll
            for (int j = 0; j < 8; ++j) acc[i][j] = 0.f;

        #pragma unroll 4
        for (int k = 0; k < K; ++k) {
            float wv[8];
            *(float4*)&wv[0] = *(const float4*)(Wp + (size_t)k * FOUT);
            *(float4*)&wv[4] = *(const float4*)(Wp + (size_t)k * FOUT + 4);
            float yv[NPT];
            #pragma unroll
            for (int i = 0; i < NPT; ++i)
                yv[i] = Ylds[(ry + i) * YS + k];
            #pragma unroll
            for (int i = 0; i < NPT; ++i)
                #pragma unroll
                for (int j = 0; j < 8; ++j)
                    acc[i][j] += yv[i] * wv[j];
        }

        float bj[8];
        #pragma unroll
        for (int j = 0; j < 8; ++j) bj[j] = Bs[w][c0 + j];
        #pragma unroll
        for (int i = 0; i < NPT; ++i)
            #pragma unroll
            for (int j = 0; j < 8; ++j) {
                float pre = fmaf(acc[i][j], IS, bj[j]);
                float t = PRECISE ? tanhf(pre) : fast_tanh(pre);
                prod[i][j] = (w == 0) ? t : prod[i][j] * t;
            }
    }

    #pragma unroll
    for (int i = 0; i < NPT; ++i) {
        int r = row0 + ry + i;
        if (r >= nRows) continue;
        if constexpr (HOUT) {
            __half2* OutH = (__half2*)Outv;
            __half2 o[4];
            #pragma unroll
            for (int j = 0; j < 4; ++j)
                o[j] = __floats2half2_rn(prod[i][2 * j] * OS, prod[i][2 * j + 1] * OS);
            *(float4*)&OutH[(size_t)r * (FOUT / 2) + (c0 >> 1)] = *(float4*)o;
        } else {
            float* Out = (float*)Outv;
            *(float4*)&Out[(size_t)r * FOUT + c0] =
                make_float4(prod[i][0] * OS, prod[i][1] * OS, prod[i][2] * OS, prod[i][3] * OS);
            *(float4*)&Out[(size_t)r * FOUT + c0 + 4] =
                make_float4(prod[i][4] * OS, prod[i][5] * OS, prod[i][6] * OS, prod[i][7] * OS);
        }
    }
}

extern "C" void kernel_launch(void* const* d_in, const int* in_sizes, int n_in,
                              void* d_out, int out_size, void* d_ws, size_t ws_size,
                              hipStream_t stream)
{
    const float* h0 = (const float*)d_in[0];
    const int*   ei = (const int*)d_in[1];
    const float* ew = (const float*)d_in[2];
    const float* W1 = (const float*)d_in[3];  const float* b1 = (const float*)d_in[4];
    const float* W2 = (const float*)d_in[5];  const float* b2 = (const float*)d_in[6];
    const float* W3 = (const float*)d_in[7];  const float* b3 = (const float*)d_in[8];
    const float* W4 = (const float*)d_in[9];  const float* b4 = (const float*)d_in[10];
    const float* W5 = (const float*)d_in[11]; const float* b5 = (const float*)d_in[12];
    const float* W6 = (const float*)d_in[13]; const float* b6 = (const float*)d_in[14];

    const int N = in_sizes[0] / FDIM;
    const int E = in_sizes[2];
    const int* rowp = ei;
    const int* colp = ei + E;

    char* p = (char*)d_ws;
    auto alloc = [&](size_t bytes) -> void* {
        void* r = (void*)p;
        p += (bytes + 255) & ~(size_t)255;
        return r;
    };
    unsigned long long* packed = (unsigned long long*)alloc((size_t)N * 8);
    float* dis  = (float*)alloc((size_t)N * 4);
    int*   cnt  = (int*)  alloc((size_t)N * 4);
    int*   off  = (int*)  alloc((size_t)(N + 1) * 4);
    const int NB = (N + 255) / 256;
    int*   bsum = (int*)  alloc((size_t)NB * 4);
    int*   boff = (int*)  alloc((size_t)NB * 4);
    int2*  ep   = (int2*) alloc((size_t)E * 8);
    float* Y    = (float*)alloc((size_t)N * FDIM * 4);
    __half2* Xh = (__half2*)alloc((size_t)N * FDIM * 2);
    __half2* Hh = (__half2*)alloc((size_t)N * FDIM * 2);

    hipMemsetAsync(packed, 0, (size_t)N * 8, stream);

    const int eb = (E + 255) / 256;
    k_hist<<<eb, 256, 0, stream>>>(colp, ew, packed, E);
    k_dis<<<NB, 256, 0, stream>>>(packed, cnt, dis, N);
    k_blocksum<<<NB, 256, 0, stream>>>(cnt, bsum, N);
    k_scan_bsum<<<1, 512, 0, stream>>>(bsum, boff, NB, off, N, E);
    k_offsets<<<NB, 256, 0, stream>>>(cnt, boff, off, N);
    k_scatter<<<eb, 256, 0, stream>>>(rowp, colp, ew, dis, off, cnt, ep, E);
    k_cvt<<<(N * 32 + 255) / 256, 256, 0, stream>>>((const float4*)h0, Xh, N * 32);

    const int sb = (N + 3) / 4;     // 4 waves (nodes) per 256-thread block
    const int gb = (N + 63) / 64;   // 64-node tiles

    // Stage A: Y = A_hat @ h0 ; Hh = 2^14 * tanh(YW1+b1)*tanh(YW2+b2)*tanh(YW3+b3)
    k_spmm<<<sb, 256, 0, stream>>>(Xh, ep, off, dis, (float2*)Y, N);
    k_gemm<128, 3, false, true><<<gb, 256, 0, stream>>>(Y, 1.0f, HSCALE,
        W1, b1, W2, b2, W3, b3, Hh, N);
    // Stage B: Y = A_hat @ (Hh/2^14 implicit) ; Hh = 2^14 * tanh(2^-14 Y W4+b4)*tanh(...)
    k_spmm<<<sb, 256, 0, stream>>>(Hh, ep, off, dis, (float2*)Y, N);
    k_gemm<128, 2, false, true><<<gb, 256, 0, stream>>>(Y, HSCALE_INV, HSCALE,
        W4, b4, W5, b5, nullptr, nullptr, Hh, N);
    // Stage C: Y = A_hat @ Hh ; out = tanh(2^-14 Y W6 + b6)  (fp32, precise)
    k_spmm<<<sb, 256, 0, stream>>>(Hh, ep, off, dis, (float2*)Y, N);
    k_gemm<64, 1, true, false><<<gb, 256, 0, stream>>>(Y, HSCALE_INV, 1.0f,
        W6, b6, nullptr, nullptr, nullptr, nullptr, d_out, N);
}

// Round 4
// 826.350 us; speedup vs baseline: 1.9591x; 1.2792x over previous
//
#include <hip/hip_runtime.h>
#include <hip/hip_bf16.h>
#include <hip/hip_fp16.h>

constexpr int FDIM = 128;
#define HSCALE 16384.0f         // 2^14: |h|<1 -> scaled <16384 <= 65504, always safe
#define HSCALE_INV (1.0f/16384.0f)

typedef _Float16 f16x8 __attribute__((ext_vector_type(8)));
typedef float f32x4 __attribute__((ext_vector_type(4)));

// ---------------- packed histogram: one 64-bit atomic per edge ----------------
// bits [0,44): sum(w) in 2^-32 fixed point; bits [44,64): count
__global__ __launch_bounds__(256) void k_hist(const int* __restrict__ col,
                                              const float* __restrict__ ew,
                                              unsigned long long* __restrict__ packed, int E)
{
    int e = blockIdx.x * 256 + threadIdx.x;
    if (e >= E) return;
    int c = col[e];
    unsigned long long v = (1ull << 44) |
        (unsigned long long)((double)ew[e] * 4294967296.0);
    atomicAdd(&packed[c], v);
}

// unpack: cnt for scan, dis = rsqrt(deg+1)
__global__ __launch_bounds__(256) void k_dis(const unsigned long long* __restrict__ packed,
                                             int* __restrict__ cnt,
                                             float* __restrict__ dis, int N)
{
    int i = blockIdx.x * 256 + threadIdx.x;
    if (i >= N) return;
    unsigned long long p = packed[i];
    cnt[i] = (int)(p >> 44);
    float d = (float)((double)(p & 0xFFFFFFFFFFFull) * (1.0 / 4294967296.0)) + 1.0f;
    float m = fmaxf(d, 1e-20f);
    dis[i] = (d > 0.0f) ? (1.0f / sqrtf(m)) : 0.0f;
}

// ---------------- 2-level exclusive scan for CSR offsets ----------------
__global__ __launch_bounds__(256) void k_blocksum(const int* __restrict__ cnt,
                                                  int* __restrict__ bsum, int n)
{
    __shared__ int s[256];
    int t = threadIdx.x;
    int i = blockIdx.x * 256 + t;
    s[t] = (i < n) ? cnt[i] : 0;
    __syncthreads();
    for (int o = 128; o > 0; o >>= 1) {
        if (t < o) s[t] += s[t + o];
        __syncthreads();
    }
    if (t == 0) bsum[blockIdx.x] = s[0];
}

__global__ __launch_bounds__(512) void k_scan_bsum(const int* __restrict__ bsum,
                                                   int* __restrict__ boff, int nb,
                                                   int* __restrict__ off, int N, int E)
{
    __shared__ int s[512];
    int t = threadIdx.x;
    int v = (t < nb) ? bsum[t] : 0;
    s[t] = v;
    __syncthreads();
    for (int o = 1; o < 512; o <<= 1) {
        int u = (t >= o) ? s[t - o] : 0;
        __syncthreads();
        s[t] += u;
        __syncthreads();
    }
    if (t < nb) boff[t] = s[t] - v;   // exclusive
    if (t == 0) off[N] = E;
}

__global__ __launch_bounds__(256) void k_offsets(const int* __restrict__ cnt,
                                                 const int* __restrict__ boff,
                                                 int* __restrict__ off, int n)
{
    __shared__ int s[256];
    int t = threadIdx.x;
    int i = blockIdx.x * 256 + t;
    int v = (i < n) ? cnt[i] : 0;
    s[t] = v;
    __syncthreads();
    for (int o = 1; o < 256; o <<= 1) {
        int u = (t >= o) ? s[t - o] : 0;
        __syncthreads();
        s[t] += u;
        __syncthreads();
    }
    if (i < n) off[i] = boff[blockIdx.x] + s[t] - v;
}

// ---------------- scatter edges into CSR (atomicSub reuses cnt) ----------------
__global__ __launch_bounds__(256) void k_scatter(const int* __restrict__ row,
                                                 const int* __restrict__ col,
                                                 const float* __restrict__ ew,
                                                 const float* __restrict__ dis,
                                                 const int* __restrict__ off,
                                                 int* __restrict__ cnt,
                                                 int2* __restrict__ ep, int E)
{
    int e = blockIdx.x * 256 + threadIdx.x;
    if (e >= E) return;
    int r = row[e], c = col[e];
    float nrm = dis[r] * ew[e] * dis[c];
    int old = atomicSub(&cnt[c], 1);        // old in [1..cnt]
    int pos = off[c + 1] - old;             // in [off[c], off[c+1])
    ep[pos] = make_int2(r, __float_as_int(nrm));
}

// ---------------- f32 -> f16 convert (stage A input) ----------------
__global__ __launch_bounds__(256) void k_cvt(const float4* __restrict__ in,
                                             __half2* __restrict__ out, int n4)
{
    int i = blockIdx.x * 256 + threadIdx.x;
    if (i >= n4) return;
    float4 v = in[i];
    __half2 a = __floats2half2_rn(v.x, v.y);
    __half2 b = __floats2half2_rn(v.z, v.w);
    float2 pk;
    ((__half2*)&pk)[0] = a;
    ((__half2*)&pk)[1] = b;
    *(float2*)&out[(size_t)i * 2] = pk;
}

// ---------------- W (f32 [128][N]) -> Wt (f16 [N][128]) transpose ----------------
__global__ __launch_bounds__(256) void k_wt(const float* __restrict__ W,
                                            __half* __restrict__ Wt, int N)
{
    int idx = blockIdx.x * 256 + threadIdx.x;
    if (idx >= N * 128) return;
    int n = idx >> 7, k = idx & 127;
    Wt[idx] = __float2half(W[(size_t)k * N + n]);
}

// ---------------- SpMM: Yh = fp16(A_hat @ X) (fp16 rows, fp32 accum) ----------------
__global__ __launch_bounds__(256) void k_spmm(const __half2* __restrict__ Xh,
                                              const int2* __restrict__ ep,
                                              const int* __restrict__ off,
                                              const float* __restrict__ dis,
                                              __half2* __restrict__ Yh, int n)
{
    int gt = blockIdx.x * 256 + threadIdx.x;
    int node = gt >> 6;
    int lane = threadIdx.x & 63;
    if (node >= n) return;

    float s = dis[node];
    float sn = s * s;                       // self-loop norm
    float2 x0 = __half22float2(Xh[(size_t)node * 64 + lane]);
    float a0x = sn * x0.x, a0y = sn * x0.y;
    float a1x = 0.f, a1y = 0.f;
    float a2x = 0.f, a2y = 0.f;
    float a3x = 0.f, a3y = 0.f;

    const int e0 = off[node];
    const int cnt = off[node + 1] - e0;
    const int2* el = ep + e0;
    const int nb = cnt >> 2;
    int done = 0;

    if (nb >= 2) {
        int2 q0, q1, q2, q3;
        int2 p0 = el[0], p1 = el[1], p2 = el[2], p3 = el[3];
        q0 = el[4]; q1 = el[5]; q2 = el[6]; q3 = el[7];
        __half2 xc0 = Xh[(size_t)p0.x * 64 + lane];
        __half2 xc1 = Xh[(size_t)p1.x * 64 + lane];
        __half2 xc2 = Xh[(size_t)p2.x * 64 + lane];
        __half2 xc3 = Xh[(size_t)p3.x * 64 + lane];
        float wc0 = __int_as_float(p0.y), wc1 = __int_as_float(p1.y);
        float wc2 = __int_as_float(p2.y), wc3 = __int_as_float(p3.y);

        int b;
        #pragma unroll 2
        for (b = 0; b + 2 < nb; ++b) {
            __half2 xn0 = Xh[(size_t)q0.x * 64 + lane];
            __half2 xn1 = Xh[(size_t)q1.x * 64 + lane];
            __half2 xn2 = Xh[(size_t)q2.x * 64 + lane];
            __half2 xn3 = Xh[(size_t)q3.x * 64 + lane];
            float wn0 = __int_as_float(q0.y), wn1 = __int_as_float(q1.y);
            float wn2 = __int_as_float(q2.y), wn3 = __int_as_float(q3.y);
            const int2* eb = el + (size_t)(b + 2) * 4;
            q0 = eb[0]; q1 = eb[1]; q2 = eb[2]; q3 = eb[3];
            float2 f0 = __half22float2(xc0), f1 = __half22float2(xc1);
            float2 f2 = __half22float2(xc2), f3 = __half22float2(xc3);
            a0x += wc0 * f0.x; a0y += wc0 * f0.y;
            a1x += wc1 * f1.x; a1y += wc1 * f1.y;
            a2x += wc2 * f2.x; a2y += wc2 * f2.y;
            a3x += wc3 * f3.x; a3y += wc3 * f3.y;
            xc0 = xn0; xc1 = xn1; xc2 = xn2; xc3 = xn3;
            wc0 = wn0; wc1 = wn1; wc2 = wn2; wc3 = wn3;
        }
        __half2 xn0 = Xh[(size_t)q0.x * 64 + lane];
        __half2 xn1 = Xh[(size_t)q1.x * 64 + lane];
        __half2 xn2 = Xh[(size_t)q2.x * 64 + lane];
        __half2 xn3 = Xh[(size_t)q3.x * 64 + lane];
        float wn0 = __int_as_float(q0.y), wn1 = __int_as_float(q1.y);
        float wn2 = __int_as_float(q2.y), wn3 = __int_as_float(q3.y);
        {
            float2 f0 = __half22float2(xc0), f1 = __half22float2(xc1);
            float2 f2 = __half22float2(xc2), f3 = __half22float2(xc3);
            a0x += wc0 * f0.x; a0y += wc0 * f0.y;
            a1x += wc1 * f1.x; a1y += wc1 * f1.y;
            a2x += wc2 * f2.x; a2y += wc2 * f2.y;
            a3x += wc3 * f3.x; a3y += wc3 * f3.y;
        }
        {
            float2 f0 = __half22float2(xn0), f1 = __half22float2(xn1);
            float2 f2 = __half22float2(xn2), f3 = __half22float2(xn3);
            a0x += wn0 * f0.x; a0y += wn0 * f0.y;
            a1x += wn1 * f1.x; a1y += wn1 * f1.y;
            a2x += wn2 * f2.x; a2y += wn2 * f2.y;
            a3x += wn3 * f3.x; a3y += wn3 * f3.y;
        }
        done = nb * 4;
    }
    for (int e = done; e < cnt; ++e) {
        int2 p = el[e];
        float2 xv = __half22float2(Xh[(size_t)p.x * 64 + lane]);
        float w = __int_as_float(p.y);
        a0x += w * xv.x; a0y += w * xv.y;
    }
    float rx = (a0x + a1x) + (a2x + a3x);
    float ry = (a0y + a1y) + (a2y + a3y);
    Yh[(size_t)node * 64 + lane] = __floats2half2_rn(rx, ry);
}

// fast tanh: 1 - 2/(e^{2x}+1) via v_exp + v_rcp
__device__ __forceinline__ float fast_tanh(float x) {
    float e = __expf(2.0f * x);
    return 1.0f - 2.0f * __builtin_amdgcn_rcpf(e + 1.0f);
}

// ---------------- MFMA GEMM: prod_{w<NW} tanh(IS*(Yh @ W_w) + b_w) ----------------
// 64 rows/block, 4 waves x 16 rows. A-frags in regs (reused across NW passes),
// B streamed from global fp16 Wt[N][128] (L1-resident), no LDS, no barriers.
// mfma_f32_16x16x32_f16: A lane(lo,hi): row=lo, k=hi*8+[0..7]; B: col=lo, same k;
// C/D: col=lane&15, row=(lane>>4)*4+reg (m89/m91-verified, dtype-independent).
template <int FOUT, int NW, bool PRECISE, bool HOUT>
__global__ __launch_bounds__(256, 4) void k_mgemm(const __half* __restrict__ Yh,
                                                  float IS, float OS,
                                                  const __half* __restrict__ Wt0, const float* __restrict__ B0,
                                                  const __half* __restrict__ Wt1, const float* __restrict__ B1,
                                                  const __half* __restrict__ Wt2, const float* __restrict__ B2,
                                                  void* __restrict__ Outv, int nRows)
{
    constexpr int NF = FOUT / 16;
    int tid = threadIdx.x;
    int wv = tid >> 6;
    int lane = tid & 63;
    int lo = lane & 15, hi = lane >> 4;
    int r0 = blockIdx.x * 64 + wv * 16;

    // A-frags: 16 VGPRs, loaded once, reused for all NW weight matrices
    f16x8 a[4];
    {
        int row = r0 + lo;
        if (row >= nRows) row = nRows - 1;
        const __half* Ap = Yh + (size_t)row * 128 + hi * 8;
        #pragma unroll
        for (int ks = 0; ks < 4; ++ks)
            a[ks] = *(const f16x8*)(Ap + ks * 32);
    }

    const __half* Wts[3] = {Wt0, Wt1, Wt2};
    const float*  Bs[3]  = {B0, B1, B2};
    float prod[NF][4];

    #pragma unroll
    for (int w = 0; w < NW; ++w) {
        const __half* Wt = Wts[w] + (size_t)lo * 128 + hi * 8;
        const float*  Bb = Bs[w];
        #pragma unroll
        for (int f = 0; f < NF; ++f) {
            const __half* Bp = Wt + (size_t)f * 16 * 128;
            f32x4 acc = {0.f, 0.f, 0.f, 0.f};
            #pragma unroll
            for (int ks = 0; ks < 4; ++ks) {
                f16x8 bfrag = *(const f16x8*)(Bp + ks * 32);
                acc = __builtin_amdgcn_mfma_f32_16x16x32_f16(a[ks], bfrag, acc, 0, 0, 0);
            }
            float bias = Bb[f * 16 + lo];
            #pragma unroll
            for (int r = 0; r < 4; ++r) {
                float pre = fmaf(acc[r], IS, bias);
                float t = PRECISE ? tanhf(pre) : fast_tanh(pre);
                prod[f][r] = (w == 0) ? t : prod[f][r] * t;
            }
        }
    }

    #pragma unroll
    for (int f = 0; f < NF; ++f) {
        int c = f * 16 + lo;
        #pragma unroll
        for (int r = 0; r < 4; ++r) {
            int row = r0 + hi * 4 + r;
            if (row < nRows) {
                if constexpr (HOUT)
                    ((__half*)Outv)[(size_t)row * FOUT + c] = __float2half(prod[f][r] * OS);
                else
                    ((float*)Outv)[(size_t)row * FOUT + c] = prod[f][r] * OS;
            }
        }
    }
}

extern "C" void kernel_launch(void* const* d_in, const int* in_sizes, int n_in,
                              void* d_out, int out_size, void* d_ws, size_t ws_size,
                              hipStream_t stream)
{
    const float* h0 = (const float*)d_in[0];
    const int*   ei = (const int*)d_in[1];
    const float* ew = (const float*)d_in[2];
    const float* W1 = (const float*)d_in[3];  const float* b1 = (const float*)d_in[4];
    const float* W2 = (const float*)d_in[5];  const float* b2 = (const float*)d_in[6];
    const float* W3 = (const float*)d_in[7];  const float* b3 = (const float*)d_in[8];
    const float* W4 = (const float*)d_in[9];  const float* b4 = (const float*)d_in[10];
    const float* W5 = (const float*)d_in[11]; const float* b5 = (const float*)d_in[12];
    const float* W6 = (const float*)d_in[13]; const float* b6 = (const float*)d_in[14];

    const int N = in_sizes[0] / FDIM;
    const int E = in_sizes[2];
    const int* rowp = ei;
    const int* colp = ei + E;

    char* p = (char*)d_ws;
    auto alloc = [&](size_t bytes) -> void* {
        void* r = (void*)p;
        p += (bytes + 255) & ~(size_t)255;
        return r;
    };
    unsigned long long* packed = (unsigned long long*)alloc((size_t)N * 8);
    float* dis  = (float*)alloc((size_t)N * 4);
    int*   cnt  = (int*)  alloc((size_t)N * 4);
    int*   off  = (int*)  alloc((size_t)(N + 1) * 4);
    const int NB = (N + 255) / 256;
    int*   bsum = (int*)  alloc((size_t)NB * 4);
    int*   boff = (int*)  alloc((size_t)NB * 4);
    int2*  ep   = (int2*) alloc((size_t)E * 8);
    __half2* Xh = (__half2*)alloc((size_t)N * FDIM * 2);
    __half2* Yh = (__half2*)alloc((size_t)N * FDIM * 2);
    __half2* Hh = (__half2*)alloc((size_t)N * FDIM * 2);
    __half* W1t = (__half*)alloc((size_t)128 * 128 * 2);
    __half* W2t = (__half*)alloc((size_t)128 * 128 * 2);
    __half* W3t = (__half*)alloc((size_t)128 * 128 * 2);
    __half* W4t = (__half*)alloc((size_t)128 * 128 * 2);
    __half* W5t = (__half*)alloc((size_t)128 * 128 * 2);
    __half* W6t = (__half*)alloc((size_t)64 * 128 * 2);

    hipMemsetAsync(packed, 0, (size_t)N * 8, stream);

    const int eb = (E + 255) / 256;
    k_hist<<<eb, 256, 0, stream>>>(colp, ew, packed, E);
    k_dis<<<NB, 256, 0, stream>>>(packed, cnt, dis, N);
    k_blocksum<<<NB, 256, 0, stream>>>(cnt, bsum, N);
    k_scan_bsum<<<1, 512, 0, stream>>>(bsum, boff, NB, off, N, E);
    k_offsets<<<NB, 256, 0, stream>>>(cnt, boff, off, N);
    k_scatter<<<eb, 256, 0, stream>>>(rowp, colp, ew, dis, off, cnt, ep, E);
    k_cvt<<<(N * 32 + 255) / 256, 256, 0, stream>>>((const float4*)h0, Xh, N * 32);
    k_wt<<<64, 256, 0, stream>>>(W1, W1t, 128);
    k_wt<<<64, 256, 0, stream>>>(W2, W2t, 128);
    k_wt<<<64, 256, 0, stream>>>(W3, W3t, 128);
    k_wt<<<64, 256, 0, stream>>>(W4, W4t, 128);
    k_wt<<<64, 256, 0, stream>>>(W5, W5t, 128);
    k_wt<<<32, 256, 0, stream>>>(W6, W6t, 64);

    const int sb = (N + 3) / 4;     // 4 waves (nodes) per 256-thread block
    const int gb = (N + 63) / 64;   // 64-row tiles

    // Stage A: Yh = A_hat @ Xh ; Hh = 2^14 * tanh(Yh W1+b1)*tanh(Yh W2+b2)*tanh(Yh W3+b3)
    k_spmm<<<sb, 256, 0, stream>>>(Xh, ep, off, dis, Yh, N);
    k_mgemm<128, 3, false, true><<<gb, 256, 0, stream>>>((const __half*)Yh, 1.0f, HSCALE,
        W1t, b1, W2t, b2, W3t, b3, Hh, N);
    // Stage B: Yh = A_hat @ Hh (2^14-scaled) ; Hh = 2^14 * tanh(2^-14 Yh W4+b4)*tanh(...)
    k_spmm<<<sb, 256, 0, stream>>>(Hh, ep, off, dis, Yh, N);
    k_mgemm<128, 2, false, true><<<gb, 256, 0, stream>>>((const __half*)Yh, HSCALE_INV, HSCALE,
        W4t, b4, W5t, b5, nullptr, nullptr, Hh, N);
    // Stage C: Yh = A_hat @ Hh ; out = tanh(2^-14 Yh W6 + b6)  (fp32, precise)
    k_spmm<<<sb, 256, 0, stream>>>(Hh, ep, off, dis, Yh, N);
    k_mgemm<64, 1, true, false><<<gb, 256, 0, stream>>>((const __half*)Yh, HSCALE_INV, 1.0f,
        W6t, b6, nullptr, nullptr, nullptr, nullptr, d_out, N);
}

// Round 5
// 642.691 us; speedup vs baseline: 2.5189x; 1.2858x over previous
//
#include <hip/hip_runtime.h>
#include <hip/hip_bf16.h>
#include <hip/hip_fp16.h>

constexpr int FDIM = 128;
#define HSCALE 16384.0f         // 2^14: |h|<1 -> scaled <16384 <= 65504, always safe
#define HSCALE_INV (1.0f/16384.0f)

typedef _Float16 f16x8 __attribute__((ext_vector_type(8)));
typedef float f32x4 __attribute__((ext_vector_type(4)));

// ===================== atomic-free CSR build: 3-level MSD partition =====================
// record: [col:17 @47][row:17 @30][ew_f16 @0]   (col < 2^17 required; N=100000 ok)
// level1: col>>11 (64 buckets); level2: (col>>5)&63; level3: col&31 (counting sort/block)
constexpr int CHUNK = 4096;     // records per partition block
constexpr int B1 = 64;
constexpr int B2 = 64;
constexpr int NC2 = 64;         // chunk slots per bucket in level-2 counts
constexpr int MAXC2 = 20;       // level-2 grid: blocks per bucket (grid-stride covers rest)

__global__ __launch_bounds__(256) void k_p1hist(const int* __restrict__ col,
                                                int* __restrict__ cnt1, int E, int NB1)
{
    __shared__ int h[B1];
    int blk = blockIdx.x, t = threadIdx.x;
    if (t < B1) h[t] = 0;
    __syncthreads();
    int base = blk * CHUNK;
    for (int i = t; i < CHUNK; i += 256) {
        int g = base + i;
        if (g < E) atomicAdd(&h[col[g] >> 11], 1);
    }
    __syncthreads();
    if (t < B1) cnt1[t * NB1 + blk] = h[t];
}

// generic exclusive-scan chain (reused for both count arrays)
__global__ __launch_bounds__(256) void k_blocksum(const int* __restrict__ cnt,
                                                  int* __restrict__ bsum, int n)
{
    __shared__ int s[256];
    int t = threadIdx.x;
    int i = blockIdx.x * 256 + t;
    s[t] = (i < n) ? cnt[i] : 0;
    __syncthreads();
    for (int o = 128; o > 0; o >>= 1) {
        if (t < o) s[t] += s[t + o];
        __syncthreads();
    }
    if (t == 0) bsum[blockIdx.x] = s[0];
}

__global__ __launch_bounds__(1024) void k_scan_bsum(const int* __restrict__ bsum,
                                                    int* __restrict__ boff, int nb,
                                                    int* __restrict__ out, int n, int total)
{
    __shared__ int s[1024];
    int t = threadIdx.x;
    int v = (t < nb) ? bsum[t] : 0;
    s[t] = v;
    __syncthreads();
    for (int o = 1; o < 1024; o <<= 1) {
        int u = (t >= o) ? s[t - o] : 0;
        __syncthreads();
        s[t] += u;
        __syncthreads();
    }
    if (t < nb) boff[t] = s[t] - v;   // exclusive
    if (t == 0) out[n] = total;
}

__global__ __launch_bounds__(256) void k_offsets(const int* __restrict__ cnt,
                                                 const int* __restrict__ boff,
                                                 int* __restrict__ out, int n)
{
    __shared__ int s[256];
    int t = threadIdx.x;
    int i = blockIdx.x * 256 + t;
    int v = (i < n) ? cnt[i] : 0;
    s[t] = v;
    __syncthreads();
    for (int o = 1; o < 256; o <<= 1) {
        int u = (t >= o) ? s[t - o] : 0;
        __syncthreads();
        s[t] += u;
        __syncthreads();
    }
    if (i < n) out[i] = boff[blockIdx.x] + s[t] - v;
}

__global__ __launch_bounds__(256) void k_p1part(const int* __restrict__ col,
                                                const int* __restrict__ row,
                                                const float* __restrict__ ew,
                                                const int* __restrict__ cnt1,
                                                const int* __restrict__ scan1,
                                                unsigned long long* __restrict__ rec1,
                                                int E, int NB1)
{
    __shared__ unsigned long long stage[CHUNK];
    __shared__ int hcnt[B1], lb[B1], gb[B1], cur[B1];
    int blk = blockIdx.x, t = threadIdx.x;
    if (t < B1) {
        hcnt[t] = cnt1[t * NB1 + blk];
        gb[t]   = scan1[t * NB1 + blk];
    }
    __syncthreads();
    if (t == 0) {
        int run = 0;
        for (int b = 0; b < B1; ++b) { lb[b] = run; run += hcnt[b]; }
    }
    __syncthreads();
    if (t < B1) cur[t] = lb[t];
    __syncthreads();
    int base = blk * CHUNK;
    for (int i = t; i < CHUNK; i += 256) {
        int g = base + i;
        if (g < E) {
            int c = col[g], r = row[g];
            unsigned long long rc = ((unsigned long long)c << 47) |
                                    ((unsigned long long)r << 30) |
                                    (unsigned long long)__half_as_ushort(__float2half(ew[g]));
            int p = atomicAdd(&cur[c >> 11], 1);
            stage[p] = rc;
        }
    }
    __syncthreads();
    int here = min(CHUNK, E - base);
    for (int j = t; j < here; j += 256) {
        unsigned long long rc = stage[j];
        int b = (int)(rc >> 58);
        rec1[gb[b] + (j - lb[b])] = rc;
    }
}

__global__ __launch_bounds__(256) void k_p2hist(const unsigned long long* __restrict__ rec1,
                                                const int* __restrict__ scan1,
                                                int* __restrict__ cnt2, int NB1)
{
    __shared__ int h[B2];
    int b = blockIdx.x / MAXC2, ci = blockIdx.x % MAXC2, t = threadIdx.x;
    int S1 = scan1[b * NB1];
    int S2 = scan1[(b + 1) * NB1];
    int size = S2 - S1;
    for (int c = ci; c * CHUNK < size && c < NC2; c += MAXC2) {
        __syncthreads();
        if (t < B2) h[t] = 0;
        __syncthreads();
        int cb = S1 + c * CHUNK, ce = min(cb + CHUNK, S2);
        for (int i = cb + t; i < ce; i += 256)
            atomicAdd(&h[(int)((rec1[i] >> 52) & 63)], 1);
        __syncthreads();
        if (t < B2) cnt2[(b * B2 + t) * NC2 + c] = h[t];
    }
}

__global__ __launch_bounds__(256) void k_p2part(const unsigned long long* __restrict__ rec1,
                                                const int* __restrict__ scan1,
                                                const int* __restrict__ cnt2,
                                                const int* __restrict__ scan2,
                                                unsigned long long* __restrict__ rec2, int NB1)
{
    __shared__ unsigned long long stage[CHUNK];
    __shared__ int hcnt[B2], lb[B2], gb[B2], cur[B2];
    int b = blockIdx.x / MAXC2, ci = blockIdx.x % MAXC2, t = threadIdx.x;
    int S1 = scan1[b * NB1];
    int S2 = scan1[(b + 1) * NB1];
    int size = S2 - S1;
    for (int c = ci; c * CHUNK < size && c < NC2; c += MAXC2) {
        __syncthreads();
        if (t < B2) {
            hcnt[t] = cnt2[(b * B2 + t) * NC2 + c];
            gb[t]   = scan2[(b * B2 + t) * NC2 + c];
        }
        __syncthreads();
        if (t == 0) {
            int run = 0;
            for (int sb = 0; sb < B2; ++sb) { lb[sb] = run; run += hcnt[sb]; }
        }
        __syncthreads();
        if (t < B2) cur[t] = lb[t];
        __syncthreads();
        int cb = S1 + c * CHUNK, ce = min(cb + CHUNK, S2);
        for (int i = cb + t; i < ce; i += 256) {
            unsigned long long rc = rec1[i];
            int p = atomicAdd(&cur[(int)((rc >> 52) & 63)], 1);
            stage[p] = rc;
        }
        __syncthreads();
        int here = ce - cb;
        for (int j = t; j < here; j += 256) {
            unsigned long long rc = stage[j];
            int sb = (int)((rc >> 52) & 63);
            rec2[gb[sb] + (j - lb[sb])] = rc;
        }
    }
}

// final: counting sort per 32-node sub-bucket; emits ep=(row, ew_f32), off, deg
__global__ __launch_bounds__(256) void k_p3(const unsigned long long* __restrict__ rec2,
                                            const int* __restrict__ scan2,
                                            int2* __restrict__ ep, int* __restrict__ off,
                                            float* __restrict__ deg, int N, int E)
{
    __shared__ int h[32], lb[32], cur[32];
    __shared__ float dg[32];
    int g = blockIdx.x, t = threadIdx.x;
    int S1 = scan2[g * NC2];
    int S2 = scan2[(g + 1) * NC2];
    if (t < 32) { h[t] = 0; dg[t] = 0.f; }
    __syncthreads();
    for (int i = S1 + t; i < S2; i += 256) {
        unsigned long long rc = rec2[i];
        int nl = (int)((rc >> 47) & 31);
        atomicAdd(&h[nl], 1);
        atomicAdd(&dg[nl], __half2float(__ushort_as_half((unsigned short)(rc & 0xFFFF))));
    }
    __syncthreads();
    if (t == 0) {
        int run = S1;
        for (int k = 0; k < 32; ++k) { lb[k] = run; run += h[k]; }
    }
    __syncthreads();
    if (t < 32) {
        cur[t] = lb[t];
        int node = g * 32 + t;
        if (node < N) { off[node] = lb[t]; deg[node] = dg[t]; }
    }
    if (g == 0 && t == 0) off[N] = E;
    __syncthreads();
    for (int i = S1 + t; i < S2; i += 256) {
        unsigned long long rc = rec2[i];
        int nl = (int)((rc >> 47) & 31);
        int p = atomicAdd(&cur[nl], 1);
        float w = __half2float(__ushort_as_half((unsigned short)(rc & 0xFFFF)));
        ep[p] = make_int2((int)((rc >> 30) & 0x1FFFF), __float_as_int(w));
    }
}

__global__ __launch_bounds__(256) void k_dis(const float* __restrict__ deg,
                                             float* __restrict__ dis, int N)
{
    int i = blockIdx.x * 256 + threadIdx.x;
    if (i >= N) return;
    float d = deg[i] + 1.0f;                  // self-loop; d >= 1 always
    dis[i] = 1.0f / sqrtf(d);
}

// patch ep.y: ew -> norm = dis[row]*ew*dis[col]
__global__ __launch_bounds__(256) void k_norm(int2* __restrict__ ep,
                                              const int* __restrict__ off,
                                              const float* __restrict__ dis, int n)
{
    int gt = blockIdx.x * 256 + threadIdx.x;
    int node = gt >> 6;
    int lane = threadIdx.x & 63;
    if (node >= n) return;
    float dc = dis[node];
    int e1 = off[node + 1];
    for (int e = off[node] + lane; e < e1; e += 64) {
        int2 p = ep[e];
        ep[e] = make_int2(p.x, __float_as_int(dis[p.x] * __int_as_float(p.y) * dc));
    }
}

// ---------------- f32 -> f16 convert (stage A input) ----------------
__global__ __launch_bounds__(256) void k_cvt(const float4* __restrict__ in,
                                             __half2* __restrict__ out, int n4)
{
    int i = blockIdx.x * 256 + threadIdx.x;
    if (i >= n4) return;
    float4 v = in[i];
    __half2 a = __floats2half2_rn(v.x, v.y);
    __half2 b = __floats2half2_rn(v.z, v.w);
    float2 pk;
    ((__half2*)&pk)[0] = a;
    ((__half2*)&pk)[1] = b;
    *(float2*)&out[(size_t)i * 2] = pk;
}

// ---------------- W (f32 [128][N]) -> Wt (f16 [N][128]) transpose ----------------
__global__ __launch_bounds__(256) void k_wt(const float* __restrict__ W,
                                            __half* __restrict__ Wt, int N)
{
    int idx = blockIdx.x * 256 + threadIdx.x;
    if (idx >= N * 128) return;
    int n = idx >> 7, k = idx & 127;
    Wt[idx] = __float2half(W[(size_t)k * N + n]);
}

// ---------------- SpMM: Yh = fp16(A_hat @ X) (fp16 rows, fp32 accum) ----------------
__global__ __launch_bounds__(256) void k_spmm(const __half2* __restrict__ Xh,
                                              const int2* __restrict__ ep,
                                              const int* __restrict__ off,
                                              const float* __restrict__ dis,
                                              __half2* __restrict__ Yh, int n)
{
    int gt = blockIdx.x * 256 + threadIdx.x;
    int node = gt >> 6;
    int lane = threadIdx.x & 63;
    if (node >= n) return;

    float s = dis[node];
    float sn = s * s;                       // self-loop norm
    float2 x0 = __half22float2(Xh[(size_t)node * 64 + lane]);
    float a0x = sn * x0.x, a0y = sn * x0.y;
    float a1x = 0.f, a1y = 0.f;
    float a2x = 0.f, a2y = 0.f;
    float a3x = 0.f, a3y = 0.f;

    const int e0 = off[node];
    const int cnt = off[node + 1] - e0;
    const int2* el = ep + e0;
    const int nb = cnt >> 2;
    int done = 0;

    if (nb >= 2) {
        int2 q0, q1, q2, q3;
        int2 p0 = el[0], p1 = el[1], p2 = el[2], p3 = el[3];
        q0 = el[4]; q1 = el[5]; q2 = el[6]; q3 = el[7];
        __half2 xc0 = Xh[(size_t)p0.x * 64 + lane];
        __half2 xc1 = Xh[(size_t)p1.x * 64 + lane];
        __half2 xc2 = Xh[(size_t)p2.x * 64 + lane];
        __half2 xc3 = Xh[(size_t)p3.x * 64 + lane];
        float wc0 = __int_as_float(p0.y), wc1 = __int_as_float(p1.y);
        float wc2 = __int_as_float(p2.y), wc3 = __int_as_float(p3.y);

        int b;
        #pragma unroll 2
        for (b = 0; b + 2 < nb; ++b) {
            __half2 xn0 = Xh[(size_t)q0.x * 64 + lane];
            __half2 xn1 = Xh[(size_t)q1.x * 64 + lane];
            __half2 xn2 = Xh[(size_t)q2.x * 64 + lane];
            __half2 xn3 = Xh[(size_t)q3.x * 64 + lane];
            float wn0 = __int_as_float(q0.y), wn1 = __int_as_float(q1.y);
            float wn2 = __int_as_float(q2.y), wn3 = __int_as_float(q3.y);
            const int2* eb = el + (size_t)(b + 2) * 4;
            q0 = eb[0]; q1 = eb[1]; q2 = eb[2]; q3 = eb[3];
            float2 f0 = __half22float2(xc0), f1 = __half22float2(xc1);
            float2 f2 = __half22float2(xc2), f3 = __half22float2(xc3);
            a0x += wc0 * f0.x; a0y += wc0 * f0.y;
            a1x += wc1 * f1.x; a1y += wc1 * f1.y;
            a2x += wc2 * f2.x; a2y += wc2 * f2.y;
            a3x += wc3 * f3.x; a3y += wc3 * f3.y;
            xc0 = xn0; xc1 = xn1; xc2 = xn2; xc3 = xn3;
            wc0 = wn0; wc1 = wn1; wc2 = wn2; wc3 = wn3;
        }
        __half2 xn0 = Xh[(size_t)q0.x * 64 + lane];
        __half2 xn1 = Xh[(size_t)q1.x * 64 + lane];
        __half2 xn2 = Xh[(size_t)q2.x * 64 + lane];
        __half2 xn3 = Xh[(size_t)q3.x * 64 + lane];
        float wn0 = __int_as_float(q0.y), wn1 = __int_as_float(q1.y);
        float wn2 = __int_as_float(q2.y), wn3 = __int_as_float(q3.y);
        {
            float2 f0 = __half22float2(xc0), f1 = __half22float2(xc1);
            float2 f2 = __half22float2(xc2), f3 = __half22float2(xc3);
            a0x += wc0 * f0.x; a0y += wc0 * f0.y;
            a1x += wc1 * f1.x; a1y += wc1 * f1.y;
            a2x += wc2 * f2.x; a2y += wc2 * f2.y;
            a3x += wc3 * f3.x; a3y += wc3 * f3.y;
        }
        {
            float2 f0 = __half22float2(xn0), f1 = __half22float2(xn1);
            float2 f2 = __half22float2(xn2), f3 = __half22float2(xn3);
            a0x += wn0 * f0.x; a0y += wn0 * f0.y;
            a1x += wn1 * f1.x; a1y += wn1 * f1.y;
            a2x += wn2 * f2.x; a2y += wn2 * f2.y;
            a3x += wn3 * f3.x; a3y += wn3 * f3.y;
        }
        done = nb * 4;
    }
    for (int e = done; e < cnt; ++e) {
        int2 p = el[e];
        float2 xv = __half22float2(Xh[(size_t)p.x * 64 + lane]);
        float w = __int_as_float(p.y);
        a0x += w * xv.x; a0y += w * xv.y;
    }
    float rx = (a0x + a1x) + (a2x + a3x);
    float ry = (a0y + a1y) + (a2y + a3y);
    Yh[(size_t)node * 64 + lane] = __floats2half2_rn(rx, ry);
}

// fast tanh: 1 - 2/(e^{2x}+1) via v_exp + v_rcp
__device__ __forceinline__ float fast_tanh(float x) {
    float e = __expf(2.0f * x);
    return 1.0f - 2.0f * __builtin_amdgcn_rcpf(e + 1.0f);
}

// ---------------- MFMA GEMM: prod_{w<NW} tanh(IS*(Yh @ W_w) + b_w) ----------------
template <int FOUT, int NW, bool PRECISE, bool HOUT>
__global__ __launch_bounds__(256, 4) void k_mgemm(const __half* __restrict__ Yh,
                                                  float IS, float OS,
                                                  const __half* __restrict__ Wt0, const float* __restrict__ B0,
                                                  const __half* __restrict__ Wt1, const float* __restrict__ B1,
                                                  const __half* __restrict__ Wt2, const float* __restrict__ B2,
                                                  void* __restrict__ Outv, int nRows)
{
    constexpr int NF = FOUT / 16;
    int tid = threadIdx.x;
    int wv = tid >> 6;
    int lane = tid & 63;
    int lo = lane & 15, hi = lane >> 4;
    int r0 = blockIdx.x * 64 + wv * 16;

    f16x8 a[4];
    {
        int row = r0 + lo;
        if (row >= nRows) row = nRows - 1;
        const __half* Ap = Yh + (size_t)row * 128 + hi * 8;
        #pragma unroll
        for (int ks = 0; ks < 4; ++ks)
            a[ks] = *(const f16x8*)(Ap + ks * 32);
    }

    const __half* Wts[3] = {Wt0, Wt1, Wt2};
    const float*  Bs[3]  = {B0, B1, B2};
    float prod[NF][4];

    #pragma unroll
    for (int w = 0; w < NW; ++w) {
        const __half* Wt = Wts[w] + (size_t)lo * 128 + hi * 8;
        const float*  Bb = Bs[w];
        #pragma unroll
        for (int f = 0; f < NF; ++f) {
            const __half* Bp = Wt + (size_t)f * 16 * 128;
            f32x4 acc = {0.f, 0.f, 0.f, 0.f};
            #pragma unroll
            for (int ks = 0; ks < 4; ++ks) {
                f16x8 bfrag = *(const f16x8*)(Bp + ks * 32);
                acc = __builtin_amdgcn_mfma_f32_16x16x32_f16(a[ks], bfrag, acc, 0, 0, 0);
            }
            float bias = Bb[f * 16 + lo];
            #pragma unroll
            for (int r = 0; r < 4; ++r) {
                float pre = fmaf(acc[r], IS, bias);
                float t = PRECISE ? tanhf(pre) : fast_tanh(pre);
                prod[f][r] = (w == 0) ? t : prod[f][r] * t;
            }
        }
    }

    #pragma unroll
    for (int f = 0; f < NF; ++f) {
        int c = f * 16 + lo;
        #pragma unroll
        for (int r = 0; r < 4; ++r) {
            int row = r0 + hi * 4 + r;
            if (row < nRows) {
                if constexpr (HOUT)
                    ((__half*)Outv)[(size_t)row * FOUT + c] = __float2half(prod[f][r] * OS);
                else
                    ((float*)Outv)[(size_t)row * FOUT + c] = prod[f][r] * OS;
            }
        }
    }
}

extern "C" void kernel_launch(void* const* d_in, const int* in_sizes, int n_in,
                              void* d_out, int out_size, void* d_ws, size_t ws_size,
                              hipStream_t stream)
{
    const float* h0 = (const float*)d_in[0];
    const int*   ei = (const int*)d_in[1];
    const float* ew = (const float*)d_in[2];
    const float* W1 = (const float*)d_in[3];  const float* b1 = (const float*)d_in[4];
    const float* W2 = (const float*)d_in[5];  const float* b2 = (const float*)d_in[6];
    const float* W3 = (const float*)d_in[7];  const float* b3 = (const float*)d_in[8];
    const float* W4 = (const float*)d_in[9];  const float* b4 = (const float*)d_in[10];
    const float* W5 = (const float*)d_in[11]; const float* b5 = (const float*)d_in[12];
    const float* W6 = (const float*)d_in[13]; const float* b6 = (const float*)d_in[14];

    const int N = in_sizes[0] / FDIM;
    const int E = in_sizes[2];
    const int* rowp = ei;
    const int* colp = ei + E;

    const int NB1 = (E + CHUNK - 1) / CHUNK;        // level-1 partition blocks
    const int n1  = B1 * NB1;                        // level-1 counts size
    const int n2  = B1 * B2 * NC2;                   // level-2 counts size (fixed 262144)
    const int NBs1 = (n1 + 255) / 256;
    const int NBs2 = (n2 + 255) / 256;               // 1024

    char* p = (char*)d_ws;
    auto alloc = [&](size_t bytes) -> void* {
        void* r = (void*)p;
        p += (bytes + 255) & ~(size_t)255;
        return r;
    };
    int* cnt1  = (int*)alloc((size_t)(n1 + 1) * 4);
    int* scan1 = (int*)alloc((size_t)(n1 + 1) * 4);
    int* cnt2  = (int*)alloc((size_t)(n2 + 1) * 4);
    int* scan2 = (int*)alloc((size_t)(n2 + 1) * 4);
    int* bsum  = (int*)alloc((size_t)1024 * 4);
    int* boff  = (int*)alloc((size_t)1024 * 4);
    int* off   = (int*)alloc((size_t)(N + 1) * 4);
    float* deg = (float*)alloc((size_t)N * 4);
    float* dis = (float*)alloc((size_t)N * 4);
    unsigned long long* rec1 = (unsigned long long*)alloc((size_t)E * 8);  // -> aliased by ep
    unsigned long long* rec2 = (unsigned long long*)alloc((size_t)E * 8);  // -> aliased by Yh
    __half2* Xh = (__half2*)alloc((size_t)N * FDIM * 2);
    __half2* Hh = (__half2*)alloc((size_t)N * FDIM * 2);
    __half* W1t = (__half*)alloc((size_t)128 * 128 * 2);
    __half* W2t = (__half*)alloc((size_t)128 * 128 * 2);
    __half* W3t = (__half*)alloc((size_t)128 * 128 * 2);
    __half* W4t = (__half*)alloc((size_t)128 * 128 * 2);
    __half* W5t = (__half*)alloc((size_t)128 * 128 * 2);
    __half* W6t = (__half*)alloc((size_t)64 * 128 * 2);

    int2*    ep = (int2*)rec1;       // rec1 dead after k_p2part
    __half2* Yh = (__half2*)rec2;    // rec2 dead after k_p3

    hipMemsetAsync(cnt2, 0, (size_t)(n2 + 1) * 4, stream);

    // ---- build ----
    k_p1hist<<<NB1, 256, 0, stream>>>(colp, cnt1, E, NB1);
    k_blocksum<<<NBs1, 256, 0, stream>>>(cnt1, bsum, n1);
    k_scan_bsum<<<1, 1024, 0, stream>>>(bsum, boff, NBs1, scan1, n1, E);
    k_offsets<<<NBs1, 256, 0, stream>>>(cnt1, boff, scan1, n1);
    k_p1part<<<NB1, 256, 0, stream>>>(colp, rowp, ew, cnt1, scan1, rec1, E, NB1);
    k_p2hist<<<B1 * MAXC2, 256, 0, stream>>>(rec1, scan1, cnt2, NB1);
    k_blocksum<<<NBs2, 256, 0, stream>>>(cnt2, bsum, n2);
    k_scan_bsum<<<1, 1024, 0, stream>>>(bsum, boff, NBs2, scan2, n2, E);
    k_offsets<<<NBs2, 256, 0, stream>>>(cnt2, boff, scan2, n2);
    k_p2part<<<B1 * MAXC2, 256, 0, stream>>>(rec1, scan1, cnt2, scan2, rec2, NB1);
    k_p3<<<B1 * B2, 256, 0, stream>>>(rec2, scan2, ep, off, deg, N, E);
    const int NBn = (N + 255) / 256;
    k_dis<<<NBn, 256, 0, stream>>>(deg, dis, N);
    const int sb = (N + 3) / 4;
    k_norm<<<sb, 256, 0, stream>>>(ep, off, dis, N);

    // ---- dense prep ----
    k_cvt<<<(N * 32 + 255) / 256, 256, 0, stream>>>((const float4*)h0, Xh, N * 32);
    k_wt<<<64, 256, 0, stream>>>(W1, W1t, 128);
    k_wt<<<64, 256, 0, stream>>>(W2, W2t, 128);
    k_wt<<<64, 256, 0, stream>>>(W3, W3t, 128);
    k_wt<<<64, 256, 0, stream>>>(W4, W4t, 128);
    k_wt<<<64, 256, 0, stream>>>(W5, W5t, 128);
    k_wt<<<32, 256, 0, stream>>>(W6, W6t, 64);

    const int gb = (N + 63) / 64;

    // Stage A
    k_spmm<<<sb, 256, 0, stream>>>(Xh, ep, off, dis, Yh, N);
    k_mgemm<128, 3, false, true><<<gb, 256, 0, stream>>>((const __half*)Yh, 1.0f, HSCALE,
        W1t, b1, W2t, b2, W3t, b3, Hh, N);
    // Stage B
    k_spmm<<<sb, 256, 0, stream>>>(Hh, ep, off, dis, Yh, N);
    k_mgemm<128, 2, false, true><<<gb, 256, 0, stream>>>((const __half*)Yh, HSCALE_INV, HSCALE,
        W4t, b4, W5t, b5, nullptr, nullptr, Hh, N);
    // Stage C
    k_spmm<<<sb, 256, 0, stream>>>(Hh, ep, off, dis, Yh, N);
    k_mgemm<64, 1, true, false><<<gb, 256, 0, stream>>>((const __half*)Yh, HSCALE_INV, 1.0f,
        W6t, b6, nullptr, nullptr, nullptr, nullptr, d_out, N);
}